// Round 11
// baseline (489.326 us; speedup 1.0000x reference)
//
#include <hip/hip_runtime.h>
#include <hip/hip_fp16.h>

#define DFEAT 128
#define BNODES 256          // nodes per bucket (dst >> 8)
#define BSHIFT 8
#define B1CHUNK 4096        // edges per bin block (391 blocks)
#define SLABC 8192          // slab capacity per bucket (avg 4096, sigma ~64)
#define TPB_TILES 2         // staged GEMM tiles per block (R6 proven)
#define TPB1 2              // fused gemm1 tiles per block

typedef _Float16 f16x8 __attribute__((ext_vector_type(8)));
typedef _Float16 f16x4 __attribute__((ext_vector_type(4)));
typedef float f32x4 __attribute__((ext_vector_type(4)));

// Column permutation: col c stored at p(c) = (c&15)*8 + (c>>4); inverse c(p) = (p&7)*16 + (p>>3).
// Layer-1 dinv split: gemm1 writes RAW f16(x·W1); aggW applies dinv[c] per edge (L2-resident).
// Layers 2/3: dinv folded into gemm epilogue; agg is a plain sum.
//
// Agg XCD partitioning: blocks dispatch round-robin over the 8 XCDs (bid%8 ~ XCD).
// Each agg wave covers ONE node x ONE 128-B feature-half, half = blockIdx&1 ->
// even XCDs only touch bytes [0,128) of every T row, odd XCDs only [128,256):
// per-XCD gather universe halves (25.6 -> 12.8 MB) -> L2 hit rate up, FETCH down.
// 1 feature/lane, 2-B loads; 64 lanes = 128 B = one L2 line per edge per wave.
// Per-feature accumulation order identical to the full-row version (bit-identical).

// ---- one-time W pre-pack into B-fragment order + permuted biases + gcnt zero ----
__global__ __launch_bounds__(256) void packW_k(const float* __restrict__ W0, const float* __restrict__ W1,
                                               const float* __restrict__ W2,
                                               const float* __restrict__ b0, const float* __restrict__ b1,
                                               const float* __restrict__ b2,
                                               _Float16* __restrict__ wpk, float* __restrict__ bp,
                                               int* __restrict__ gcnt) {
    int idx = blockIdx.x * 256 + threadIdx.x;   // 0 .. 3*16384-1
    int layer = idx >> 14;
    int e = idx & 16383;
    int k = e >> 7;
    int nn = e & 127;
    const float* W = (layer == 0) ? W0 : ((layer == 1) ? W1 : W2);
    int ksrc = (layer == 0) ? k : (((k & 7) << 4) | (k >> 3));
    float v = W[ksrc * DFEAT + nn];
    int kc = k >> 5, quad = (k >> 3) & 3, j = k & 7;
    int ct = nn >> 4;
    int pos = ((ct * 4 + kc) * 64 + quad * 16 + (nn & 15)) * 8 + j;
    wpk[(size_t)layer * 16384 + pos] = (_Float16)v;
    if (idx < 384) {
        int l = idx >> 7, p = idx & 127;
        int c = ((p & 7) << 4) | (p >> 3);
        const float* bb = (l == 0) ? b0 : ((l == 1) ? b1 : b2);
        bp[l * 128 + p] = bb[c];
    }
    if (idx < 512) gcnt[idx] = 0;
}

__device__ inline f16x8 ldA8(const float* p) {
    float4 a = *(const float4*)p;
    float4 b = *(const float4*)(p + 4);
    return f16x8{(_Float16)a.x, (_Float16)a.y, (_Float16)a.z, (_Float16)a.w,
                 (_Float16)b.x, (_Float16)b.y, (_Float16)b.z, (_Float16)b.w};
}
__device__ inline f16x8 ldA8(const __half* p) { return *(const f16x8*)p; }
__device__ inline f16x8 zero8() {
    return f16x8{(_Float16)0.f, (_Float16)0.f, (_Float16)0.f, (_Float16)0.f,
                 (_Float16)0.f, (_Float16)0.f, (_Float16)0.f, (_Float16)0.f};
}

// ---- fused dispatch: blocks [0,nbin) = bin; blocks [nbin, nbin+g1) = layer-1 GEMM ----
// LDS overlaid (bin 31.0 KB | gemm1 wl 32 KB -> 32 KB static). Independent work.
struct BinSh {
    int cnt[512];
    int off[512];
    int gbase[512];
    int sd[256];
    unsigned int buf[B1CHUNK];
    unsigned short bid[B1CHUNK];
};
struct G1Sh {
    _Float16 wl[16384];
};

__global__ __launch_bounds__(256) void binGemm1_k(const int* __restrict__ src, const int* __restrict__ dst,
                                                  int* __restrict__ gcnt, unsigned int* __restrict__ slab,
                                                  int E, int nbuck, int nbin,
                                                  const float* __restrict__ A, const _Float16* __restrict__ wfrag,
                                                  __half* __restrict__ C, int n, int ntiles) {
    __shared__ __align__(16) char smem[32768];
    int t = threadIdx.x;
    if (blockIdx.x >= nbin) {
        // ---- layer-1 GEMM: C_perm = raw f16(A @ W1), direct-A, no dinv ----
        _Float16* wl = ((G1Sh*)smem)->wl;
        const int wv_ = t >> 6;
        const int lane = t & 63;
        const int m = lane & 15;
        const int q = lane >> 4;
        for (int c = t; c < 2048; c += 256)
            *(f16x8*)&wl[c * 8] = *(const f16x8*)&wfrag[c * 8];
        __syncthreads();
        int t0 = (blockIdx.x - nbin) * TPB1;
        int tend = t0 + TPB1;
        if (tend > ntiles) tend = ntiles;
        for (int tile = t0; tile < tend; ++tile) {
            int row0 = tile * 64;
            int ga = row0 + wv_ * 16 + m;
            f16x8 af[4];
            if (ga < n) {
#pragma unroll
                for (int kc = 0; kc < 4; ++kc)
                    af[kc] = ldA8(&A[(size_t)ga * DFEAT + kc * 32 + q * 8]);
            } else {
#pragma unroll
                for (int kc = 0; kc < 4; ++kc) af[kc] = zero8();
            }
            f32x4 acc[8];
#pragma unroll
            for (int ct = 0; ct < 8; ++ct) acc[ct] = (f32x4){0.f, 0.f, 0.f, 0.f};
#pragma unroll
            for (int ct = 0; ct < 8; ++ct) {
#pragma unroll
                for (int kc = 0; kc < 4; ++kc) {
                    f16x8 bf = *(f16x8*)&wl[((ct * 4 + kc) * 64 + lane) * 8];
                    acc[ct] = __builtin_amdgcn_mfma_f32_16x16x32_f16(af[kc], bf, acc[ct], 0, 0, 0);
                }
            }
            const int rbase = row0 + wv_ * 16 + q * 4;
#pragma unroll
            for (int r = 0; r < 4; ++r) {
                int gr = rbase + r;
                if (gr < n) {
                    f16x8 o;
#pragma unroll
                    for (int ct = 0; ct < 8; ++ct) o[ct] = (_Float16)acc[ct][r];
                    *(f16x8*)&C[(size_t)gr * DFEAT + m * 8] = o;
                }
            }
        }
        return;
    }
    // ---- bin body (R6-proven, via overlay) ----
    BinSh* B = (BinSh*)smem;
    int base = blockIdx.x * B1CHUNK;
    int nloc = E - base;
    if (nloc > B1CHUNK) nloc = B1CHUNK;
    B->cnt[t] = 0;
    B->cnt[t + 256] = 0;
    __syncthreads();
    int k = t;
    for (; k + 768 < nloc; k += 1024) {
        int d0 = dst[base + k], d1 = dst[base + k + 256], d2 = dst[base + k + 512], d3 = dst[base + k + 768];
        atomicAdd(&B->cnt[d0 >> BSHIFT], 1);
        atomicAdd(&B->cnt[d1 >> BSHIFT], 1);
        atomicAdd(&B->cnt[d2 >> BSHIFT], 1);
        atomicAdd(&B->cnt[d3 >> BSHIFT], 1);
    }
    for (; k < nloc; k += 256) atomicAdd(&B->cnt[dst[base + k] >> BSHIFT], 1);
    __syncthreads();
    int v0 = B->cnt[2 * t], v1 = B->cnt[2 * t + 1];
    int tsum = v0 + v1;
    B->sd[t] = tsum;
    __syncthreads();
    for (int o = 1; o < 256; o <<= 1) {
        int x = (t >= o) ? B->sd[t - o] : 0;
        __syncthreads();
        B->sd[t] += x;
        __syncthreads();
    }
    int texcl = B->sd[t] - tsum;
    B->off[2 * t] = texcl;
    B->off[2 * t + 1] = texcl + v0;
    if (2 * t < nbuck && v0 > 0) B->gbase[2 * t] = atomicAdd(&gcnt[2 * t], v0);
    if (2 * t + 1 < nbuck && v1 > 0) B->gbase[2 * t + 1] = atomicAdd(&gcnt[2 * t + 1], v1);
    __syncthreads();
    k = t;
    for (; k + 768 < nloc; k += 1024) {
        int d0 = dst[base + k], d1 = dst[base + k + 256], d2 = dst[base + k + 512], d3 = dst[base + k + 768];
        int s0 = src[base + k], s1 = src[base + k + 256], s2 = src[base + k + 512], s3 = src[base + k + 768];
        int b0_ = d0 >> BSHIFT, b1_ = d1 >> BSHIFT, b2_ = d2 >> BSHIFT, b3_ = d3 >> BSHIFT;
        int r0 = atomicAdd(&B->off[b0_], 1); B->buf[r0] = ((unsigned)s0 << BSHIFT) | (unsigned)(d0 & (BNODES - 1)); B->bid[r0] = (unsigned short)b0_;
        int r1 = atomicAdd(&B->off[b1_], 1); B->buf[r1] = ((unsigned)s1 << BSHIFT) | (unsigned)(d1 & (BNODES - 1)); B->bid[r1] = (unsigned short)b1_;
        int r2 = atomicAdd(&B->off[b2_], 1); B->buf[r2] = ((unsigned)s2 << BSHIFT) | (unsigned)(d2 & (BNODES - 1)); B->bid[r2] = (unsigned short)b2_;
        int r3 = atomicAdd(&B->off[b3_], 1); B->buf[r3] = ((unsigned)s3 << BSHIFT) | (unsigned)(d3 & (BNODES - 1)); B->bid[r3] = (unsigned short)b3_;
    }
    for (; k < nloc; k += 256) {
        int d = dst[base + k];
        int s = src[base + k];
        int b = d >> BSHIFT;
        int r = atomicAdd(&B->off[b], 1);
        B->buf[r] = ((unsigned)s << BSHIFT) | (unsigned)(d & (BNODES - 1));
        B->bid[r] = (unsigned short)b;
    }
    __syncthreads();
    k = t;
    for (; k + 768 < nloc; k += 1024) {
#pragma unroll
        for (int u = 0; u < 4; ++u) {
            int kk = k + u * 256;
            int b = B->bid[kk];
            int o0 = B->off[b] - B->cnt[b];
            int pos = B->gbase[b] + (kk - o0);
            if (pos < SLABC) slab[(size_t)b * SLABC + pos] = B->buf[kk];
        }
    }
    for (; k < nloc; k += 256) {
        int b = B->bid[k];
        int o0 = B->off[b] - B->cnt[b];
        int pos = B->gbase[b] + (k - o0);
        if (pos < SLABC) slab[(size_t)b * SLABC + pos] = B->buf[k];
    }
}

// ---- Phase B2: per-bucket degree count + rp + dinv + CSR col scatter ----
__global__ __launch_bounds__(256) void bucketAB_k(const unsigned int* __restrict__ slab,
                                                  const int* __restrict__ gcnt,
                                                  int* __restrict__ rp, float* __restrict__ dinv,
                                                  int* __restrict__ cols, int N, int nbuck) {
    __shared__ int cnt[256];
    __shared__ int cur[256];
    __shared__ int psum[256];
    __shared__ int outb[SLABC];
    int t = threadIdx.x;
    int b = blockIdx.x;
    int n0 = b << BSHIFT;
    int nn = N - n0;
    if (nn > BNODES) nn = BNODES;
    int ne_raw = gcnt[b];
    int ne = ne_raw > SLABC ? SLABC : ne_raw;
    const unsigned int* sl = slab + (size_t)b * SLABC;
    int part = 0;
    for (int i = t; i < b; i += 256) part += gcnt[i];
    psum[t] = part;
    cnt[t] = 0;
    __syncthreads();
    for (int o = 128; o > 0; o >>= 1) {
        if (t < o) psum[t] += psum[t + o];
        __syncthreads();
    }
    int base = psum[0];
    int k = t;
    for (; k + 768 < ne; k += 1024) {
        unsigned a0 = sl[k], a1 = sl[k + 256], a2 = sl[k + 512], a3 = sl[k + 768];
        atomicAdd(&cnt[a0 & (BNODES - 1)], 1);
        atomicAdd(&cnt[a1 & (BNODES - 1)], 1);
        atomicAdd(&cnt[a2 & (BNODES - 1)], 1);
        atomicAdd(&cnt[a3 & (BNODES - 1)], 1);
    }
    for (; k < ne; k += 256) atomicAdd(&cnt[sl[k] & (BNODES - 1)], 1);
    __syncthreads();
    int deg = cnt[t];
    for (int o = 1; o < 256; o <<= 1) {
        int x = (t >= o) ? cnt[t - o] : 0;
        __syncthreads();
        cnt[t] += x;
        __syncthreads();
    }
    int excl = cnt[t] - deg;
    if (t < nn) {
        rp[n0 + t] = base + excl;
        dinv[n0 + t] = rsqrtf((float)(deg + 1));  // +1 self loop
    }
    if (b == nbuck - 1 && t == 0) rp[N] = base + ne_raw;
    cur[t] = excl;
    __syncthreads();
    k = t;
    for (; k + 768 < ne; k += 1024) {
        unsigned a0 = sl[k], a1 = sl[k + 256], a2 = sl[k + 512], a3 = sl[k + 768];
        int p0 = atomicAdd(&cur[a0 & (BNODES - 1)], 1); outb[p0] = (int)(a0 >> BSHIFT);
        int p1 = atomicAdd(&cur[a1 & (BNODES - 1)], 1); outb[p1] = (int)(a1 >> BSHIFT);
        int p2 = atomicAdd(&cur[a2 & (BNODES - 1)], 1); outb[p2] = (int)(a2 >> BSHIFT);
        int p3 = atomicAdd(&cur[a3 & (BNODES - 1)], 1); outb[p3] = (int)(a3 >> BSHIFT);
    }
    for (; k < ne; k += 256) {
        unsigned a = sl[k];
        int p = atomicAdd(&cur[a & (BNODES - 1)], 1);
        outb[p] = (int)(a >> BSHIFT);
    }
    __syncthreads();
    k = t;
    for (; k + 768 < ne; k += 1024) {
        int o0 = outb[k], o1 = outb[k + 256], o2 = outb[k + 512], o3 = outb[k + 768];
        cols[base + k] = o0;
        cols[base + k + 256] = o1;
        cols[base + k + 512] = o2;
        cols[base + k + 768] = o3;
    }
    for (; k < ne; k += 256) cols[base + k] = outb[k];
}

// ---------------- standalone staged GEMM (layers 2-3): R6-proven ----------------
__global__ __launch_bounds__(256) void gemmP_k(const __half* __restrict__ A, const _Float16* __restrict__ wfrag,
                                               const float* __restrict__ dinv, __half* __restrict__ C,
                                               int n, int ntiles) {
    __shared__ _Float16 al[8192];     // A frags, swizzled (16 KB)
    __shared__ _Float16 wl[16384];    // W frags, linear copy (32 KB)
    const int tid = threadIdx.x;
    const int wv_ = tid >> 6;
    const int lane = tid & 63;
    const int t0 = blockIdx.x * TPB_TILES;
    const int chunk = tid & 15;
    const int rsub = tid >> 4;
    const int kcS = chunk >> 2, quadS = chunk & 3;
    const int swzS = (kcS << 1) ^ (quadS & 1);

    for (int c = tid; c < 2048; c += 256)
        *(f16x8*)&wl[c * 8] = *(const f16x8*)&wfrag[c * 8];

    f16x8 pre[4];
    {
        int row0 = t0 * 64;
#pragma unroll
        for (int p = 0; p < 4; ++p) {
            int gr = row0 + p * 16 + rsub;
            pre[p] = (gr < n) ? ldA8(&A[(size_t)gr * DFEAT + chunk * 8]) : zero8();
        }
    }
    for (int tt = 0; tt < TPB_TILES; ++tt) {
        int tile = t0 + tt;
        if (tile >= ntiles) break;
        int row0 = tile * 64;
#pragma unroll
        for (int p = 0; p < 4; ++p) {
            int idx = (p * 4 + kcS) * 64 + quadS * 16 + rsub;
            *(f16x8*)&al[(idx ^ swzS) * 8] = pre[p];
        }
        __syncthreads();
        if (tt + 1 < TPB_TILES && tile + 1 < ntiles) {
            int nrow0 = (tile + 1) * 64;
#pragma unroll
            for (int p = 0; p < 4; ++p) {
                int gr = nrow0 + p * 16 + rsub;
                pre[p] = (gr < n) ? ldA8(&A[(size_t)gr * DFEAT + chunk * 8]) : zero8();
            }
        }
        f16x8 af[4];
        const int swzR = (lane >> 4) & 1;
#pragma unroll
        for (int kc = 0; kc < 4; ++kc) {
            int idx = (wv_ * 4 + kc) * 64 + lane;
            af[kc] = *(f16x8*)&al[(idx ^ (kc << 1) ^ swzR) * 8];
        }
        const int quad = lane >> 4, cb = lane & 15;
        const int rbase = row0 + wv_ * 16 + quad * 4;
        float ds[4];
#pragma unroll
        for (int r = 0; r < 4; ++r) ds[r] = (rbase + r < n) ? dinv[rbase + r] : 0.f;
        f32x4 acc[8];
#pragma unroll
        for (int ct = 0; ct < 8; ++ct) acc[ct] = (f32x4){0.f, 0.f, 0.f, 0.f};
#pragma unroll
        for (int ct = 0; ct < 8; ++ct) {
#pragma unroll
            for (int kc = 0; kc < 4; ++kc) {
                f16x8 bf = *(f16x8*)&wl[((ct * 4 + kc) * 64 + lane) * 8];
                acc[ct] = __builtin_amdgcn_mfma_f32_16x16x32_f16(af[kc], bf, acc[ct], 0, 0, 0);
            }
        }
#pragma unroll
        for (int r = 0; r < 4; ++r) {
            int gr = rbase + r;
            if (gr < n) {
                f16x8 o;
#pragma unroll
                for (int ct = 0; ct < 8; ++ct) o[ct] = (_Float16)(acc[ct][r] * ds[r]);
                *(f16x8*)&C[(size_t)gr * DFEAT + cb * 8] = o;
            }
        }
        __syncthreads();
    }
}

// ---------------- aggregation: XCD-partitioned feature halves ----------------
// grid = 2 * ceil(N/4) blocks; fh = blockIdx&1 selects the 128-B feature half
// (all 4 waves of a block share fh, so the block's XCD touches only that half).
// 1 feature/lane, per-edge load = 2 B/lane (128 B/wave = one L2 line).
// Accumulation order per feature identical to the full-row version.

// layer-1: per-edge weight dinv[c] (L2-resident, scalar load via SGPR c)
__global__ __launch_bounds__(256) void aggW_k(const __half* __restrict__ T, const float* __restrict__ dinv,
                                              const int* __restrict__ rowptr, const int* __restrict__ cols,
                                              const float* __restrict__ biasp, __half* __restrict__ out, int n) {
    int fh = blockIdx.x & 1;
    int wid = ((int)blockIdx.x >> 1) * 4 + (threadIdx.x >> 6);
    if (wid >= n) return;
    int lane = threadIdx.x & 63;
    int f = (fh << 6) | lane;
    float di = dinv[wid];
    float a = di * __half2float(T[(size_t)wid * DFEAT + f]);
    int s = rowptr[wid], e = rowptr[wid + 1];
    for (int p = s; p < e; ) {
        int take = e - p;
        if (take > 64) take = 64;
        int q = p + lane;
        if (q >= e) q = e - 1;
        int ci = cols[q];
        int j = 0;
        for (; j + 8 <= take; j += 8) {
            int c0 = __builtin_amdgcn_readlane(ci, j + 0);
            int c1 = __builtin_amdgcn_readlane(ci, j + 1);
            int c2 = __builtin_amdgcn_readlane(ci, j + 2);
            int c3 = __builtin_amdgcn_readlane(ci, j + 3);
            int c4 = __builtin_amdgcn_readlane(ci, j + 4);
            int c5 = __builtin_amdgcn_readlane(ci, j + 5);
            int c6 = __builtin_amdgcn_readlane(ci, j + 6);
            int c7 = __builtin_amdgcn_readlane(ci, j + 7);
            float w0 = dinv[c0], w1 = dinv[c1], w2 = dinv[c2], w3 = dinv[c3];
            float w4 = dinv[c4], w5 = dinv[c5], w6 = dinv[c6], w7 = dinv[c7];
            float v0 = __half2float(T[(size_t)c0 * DFEAT + f]);
            float v1 = __half2float(T[(size_t)c1 * DFEAT + f]);
            float v2 = __half2float(T[(size_t)c2 * DFEAT + f]);
            float v3 = __half2float(T[(size_t)c3 * DFEAT + f]);
            float v4 = __half2float(T[(size_t)c4 * DFEAT + f]);
            float v5 = __half2float(T[(size_t)c5 * DFEAT + f]);
            float v6 = __half2float(T[(size_t)c6 * DFEAT + f]);
            float v7 = __half2float(T[(size_t)c7 * DFEAT + f]);
            a += w0 * v0; a += w1 * v1; a += w2 * v2; a += w3 * v3;
            a += w4 * v4; a += w5 * v5; a += w6 * v6; a += w7 * v7;
        }
        for (; j < take; ++j) {
            int c = __builtin_amdgcn_readlane(ci, j);
            a += dinv[c] * __half2float(T[(size_t)c * DFEAT + f]);
        }
        p += take;
    }
    float o = fmaxf(di * a + biasp[f], 0.f);
    out[(size_t)wid * DFEAT + f] = __float2half(o);
}

// interior: plain sum (dinv folded in gemm epilogue), relu, f16 out
__global__ __launch_bounds__(256) void agg_k(const __half* __restrict__ T, const float* __restrict__ dinv,
                                             const int* __restrict__ rowptr, const int* __restrict__ cols,
                                             const float* __restrict__ biasp, __half* __restrict__ out, int n) {
    int fh = blockIdx.x & 1;
    int wid = ((int)blockIdx.x >> 1) * 4 + (threadIdx.x >> 6);
    if (wid >= n) return;
    int lane = threadIdx.x & 63;
    int f = (fh << 6) | lane;
    float a = __half2float(T[(size_t)wid * DFEAT + f]);
    int s = rowptr[wid], e = rowptr[wid + 1];
    for (int p = s; p < e; ) {
        int take = e - p;
        if (take > 64) take = 64;
        int q = p + lane;
        if (q >= e) q = e - 1;
        int ci = cols[q];
        int j = 0;
        for (; j + 8 <= take; j += 8) {
            int c0 = __builtin_amdgcn_readlane(ci, j + 0);
            int c1 = __builtin_amdgcn_readlane(ci, j + 1);
            int c2 = __builtin_amdgcn_readlane(ci, j + 2);
            int c3 = __builtin_amdgcn_readlane(ci, j + 3);
            int c4 = __builtin_amdgcn_readlane(ci, j + 4);
            int c5 = __builtin_amdgcn_readlane(ci, j + 5);
            int c6 = __builtin_amdgcn_readlane(ci, j + 6);
            int c7 = __builtin_amdgcn_readlane(ci, j + 7);
            float v0 = __half2float(T[(size_t)c0 * DFEAT + f]);
            float v1 = __half2float(T[(size_t)c1 * DFEAT + f]);
            float v2 = __half2float(T[(size_t)c2 * DFEAT + f]);
            float v3 = __half2float(T[(size_t)c3 * DFEAT + f]);
            float v4 = __half2float(T[(size_t)c4 * DFEAT + f]);
            float v5 = __half2float(T[(size_t)c5 * DFEAT + f]);
            float v6 = __half2float(T[(size_t)c6 * DFEAT + f]);
            float v7 = __half2float(T[(size_t)c7 * DFEAT + f]);
            a += v0; a += v1; a += v2; a += v3;
            a += v4; a += v5; a += v6; a += v7;
        }
        for (; j < take; ++j) {
            int c = __builtin_amdgcn_readlane(ci, j);
            a += __half2float(T[(size_t)c * DFEAT + f]);
        }
        p += take;
    }
    float dw = dinv[wid];
    float o = fmaxf(dw * a + biasp[f], 0.f);
    out[(size_t)wid * DFEAT + f] = __float2half(o);
}

// final: no relu, f32 out, un-permutes at store
__global__ __launch_bounds__(256) void aggF_k(const __half* __restrict__ T, const float* __restrict__ dinv,
                                              const int* __restrict__ rowptr, const int* __restrict__ cols,
                                              const float* __restrict__ biasp, float* __restrict__ out, int n) {
    int fh = blockIdx.x & 1;
    int wid = ((int)blockIdx.x >> 1) * 4 + (threadIdx.x >> 6);
    if (wid >= n) return;
    int lane = threadIdx.x & 63;
    int f = (fh << 6) | lane;
    float a = __half2float(T[(size_t)wid * DFEAT + f]);
    int s = rowptr[wid], e = rowptr[wid + 1];
    for (int p = s; p < e; ) {
        int take = e - p;
        if (take > 64) take = 64;
        int q = p + lane;
        if (q >= e) q = e - 1;
        int ci = cols[q];
        int j = 0;
        for (; j + 8 <= take; j += 8) {
            int c0 = __builtin_amdgcn_readlane(ci, j + 0);
            int c1 = __builtin_amdgcn_readlane(ci, j + 1);
            int c2 = __builtin_amdgcn_readlane(ci, j + 2);
            int c3 = __builtin_amdgcn_readlane(ci, j + 3);
            int c4 = __builtin_amdgcn_readlane(ci, j + 4);
            int c5 = __builtin_amdgcn_readlane(ci, j + 5);
            int c6 = __builtin_amdgcn_readlane(ci, j + 6);
            int c7 = __builtin_amdgcn_readlane(ci, j + 7);
            float v0 = __half2float(T[(size_t)c0 * DFEAT + f]);
            float v1 = __half2float(T[(size_t)c1 * DFEAT + f]);
            float v2 = __half2float(T[(size_t)c2 * DFEAT + f]);
            float v3 = __half2float(T[(size_t)c3 * DFEAT + f]);
            float v4 = __half2float(T[(size_t)c4 * DFEAT + f]);
            float v5 = __half2float(T[(size_t)c5 * DFEAT + f]);
            float v6 = __half2float(T[(size_t)c6 * DFEAT + f]);
            float v7 = __half2float(T[(size_t)c7 * DFEAT + f]);
            a += v0; a += v1; a += v2; a += v3;
            a += v4; a += v5; a += v6; a += v7;
        }
        for (; j < take; ++j) {
            int c = __builtin_amdgcn_readlane(ci, j);
            a += __half2float(T[(size_t)c * DFEAT + f]);
        }
        p += take;
    }
    float dw = dinv[wid];
    float o = dw * a + biasp[f];
    int c0 = ((f & 7) << 4) | (f >> 3);
    out[(size_t)wid * DFEAT + c0] = o;
}

// ---------------- launch ----------------

extern "C" void kernel_launch(void* const* d_in, const int* in_sizes, int n_in,
                              void* d_out, int out_size, void* d_ws, size_t ws_size,
                              hipStream_t stream) {
    const float* x  = (const float*)d_in[0];
    const int*   ei = (const int*)d_in[1];
    const float* W1 = (const float*)d_in[2];
    const float* b1 = (const float*)d_in[3];
    const float* W2 = (const float*)d_in[4];
    const float* b2 = (const float*)d_in[5];
    const float* W3 = (const float*)d_in[6];
    const float* b3 = (const float*)d_in[7];
    float* out = (float*)d_out;

    const int N = in_sizes[0] / DFEAT;
    const int E = in_sizes[1] / 2;
    const int* srcp = ei;
    const int* dstp = ei + E;

    size_t off = 0;
    auto alloc = [&](size_t bytes) -> void* {
        void* p = (char*)d_ws + off;
        off += (bytes + 255) & ~(size_t)255;
        return p;
    };
    const int nbuck = (N + BNODES - 1) / BNODES;       // 391 for N=100000 (<=512)

    int*    gcnt = (int*)alloc(2048);
    int*    rp   = (int*)alloc((size_t)(N + 1) * 4);
    float*  dinv = (float*)alloc((size_t)N * 4);
    _Float16* wpk = (_Float16*)alloc((size_t)3 * 16384 * 2);   // pre-packed W frags
    float*  bp   = (float*)alloc(3 * 128 * 4);                 // permuted biases
    unsigned int* slab = (unsigned int*)alloc((size_t)nbuck * SLABC * 4);
    int*    cols = (int*)alloc((size_t)E * 4);
    __half* bufA = (__half*)alloc((size_t)N * DFEAT * 2);
    __half* bufB = (__half*)alloc((size_t)N * DFEAT * 2);

    const int nbin = (E + B1CHUNK - 1) / B1CHUNK;
    int ntiles = (N + 63) / 64;
    int g1blocks = (ntiles + TPB1 - 1) / TPB1;
    int gemmGrid = (ntiles + TPB_TILES - 1) / TPB_TILES;
    int aggGrid  = 2 * ((N + 3) / 4);     // 2 feature-halves x ceil(N/4) node-groups

    // 1: W pack (zeroes gcnt).  2: fused [bin | gemm1-raw].
    packW_k<<<192, 256, 0, stream>>>(W1, W2, W3, b1, b2, b3, wpk, bp, gcnt);
    binGemm1_k<<<nbin + g1blocks, 256, 0, stream>>>(srcp, dstp, gcnt, slab, E, nbuck, nbin,
                                                    x, wpk, bufA, N, ntiles);
    bucketAB_k<<<nbuck, 256, 0, stream>>>(slab, gcnt, rp, dinv, cols, N, nbuck);

    aggW_k<<<aggGrid, 256, 0, stream>>>(bufA, dinv, rp, cols, bp, bufB, N);

    gemmP_k<<<gemmGrid, 256, 0, stream>>>(bufB, wpk + 16384, dinv, bufA, N, ntiles);
    agg_k<<<aggGrid, 256, 0, stream>>>(bufA, dinv, rp, cols, bp + 128, bufB, N);

    gemmP_k<<<gemmGrid, 256, 0, stream>>>(bufB, wpk + 32768, dinv, bufA, N, ntiles);
    aggF_k<<<aggGrid, 256, 0, stream>>>(bufA, dinv, rp, cols, bp + 256, out, N);
}

// Round 12
// 377.770 us; speedup vs baseline: 1.2953x; 1.2953x over previous
//
#include <hip/hip_runtime.h>
#include <hip/hip_fp16.h>

#define DFEAT 128
#define BNODES 256          // nodes per bucket (dst >> 8)
#define BSHIFT 8
#define B1CHUNK 4096        // edges per bin block (391 blocks)
#define SLABC 8192          // slab capacity per bucket (avg 4096, sigma ~64)
#define TPB_TILES 2         // standalone GEMM tiles per block (R6 proven)
#define TPB1 2              // fused gemm1 tiles per block

typedef _Float16 f16x8 __attribute__((ext_vector_type(8)));
typedef _Float16 f16x4 __attribute__((ext_vector_type(4)));
typedef float f32x4 __attribute__((ext_vector_type(4)));

// Column permutation: col c stored at p(c) = (c&15)*8 + (c>>4); inverse c(p) = (p&7)*16 + (p>>3).
// Layer-1 dinv split: gemm1 writes RAW f16(x·W1) so it can run concurrently with the CSR
// bin pass (dinv not yet computed); aggW applies dinv[c] per edge (L2-resident, SGPR addr).
// Layers 2/3: dinv folded into gemm epilogue; agg is a plain sum.
// This is the best-measured configuration (379.2 us). R9-R11 structural experiments all
// regressed: heterogeneous agg|gemm fusion pays a register-allocation tax (VGPR=max of
// branches -> agg occupancy halves -> fabric BW halves); feature-half XCD partitioning
// doubles gather-instruction count (request-rate bound, BW 3.7->2.2 TB/s).

// ---- one-time W pre-pack into B-fragment order + permuted biases + gcnt zero ----
__global__ __launch_bounds__(256) void packW_k(const float* __restrict__ W0, const float* __restrict__ W1,
                                               const float* __restrict__ W2,
                                               const float* __restrict__ b0, const float* __restrict__ b1,
                                               const float* __restrict__ b2,
                                               _Float16* __restrict__ wpk, float* __restrict__ bp,
                                               int* __restrict__ gcnt) {
    int idx = blockIdx.x * 256 + threadIdx.x;   // 0 .. 3*16384-1
    int layer = idx >> 14;
    int e = idx & 16383;
    int k = e >> 7;
    int nn = e & 127;
    const float* W = (layer == 0) ? W0 : ((layer == 1) ? W1 : W2);
    int ksrc = (layer == 0) ? k : (((k & 7) << 4) | (k >> 3));
    float v = W[ksrc * DFEAT + nn];
    int kc = k >> 5, quad = (k >> 3) & 3, j = k & 7;
    int ct = nn >> 4;
    int pos = ((ct * 4 + kc) * 64 + quad * 16 + (nn & 15)) * 8 + j;
    wpk[(size_t)layer * 16384 + pos] = (_Float16)v;
    if (idx < 384) {
        int l = idx >> 7, p = idx & 127;
        int c = ((p & 7) << 4) | (p >> 3);
        const float* bb = (l == 0) ? b0 : ((l == 1) ? b1 : b2);
        bp[l * 128 + p] = bb[c];
    }
    if (idx < 512) gcnt[idx] = 0;
}

__device__ inline f16x8 ldA8(const float* p) {
    float4 a = *(const float4*)p;
    float4 b = *(const float4*)(p + 4);
    return f16x8{(_Float16)a.x, (_Float16)a.y, (_Float16)a.z, (_Float16)a.w,
                 (_Float16)b.x, (_Float16)b.y, (_Float16)b.z, (_Float16)b.w};
}
__device__ inline f16x8 ldA8(const __half* p) { return *(const f16x8*)p; }
__device__ inline f16x8 zero8() {
    return f16x8{(_Float16)0.f, (_Float16)0.f, (_Float16)0.f, (_Float16)0.f,
                 (_Float16)0.f, (_Float16)0.f, (_Float16)0.f, (_Float16)0.f};
}

// ---- fused dispatch: blocks [0,nbin) = bin; blocks [nbin, nbin+g1) = layer-1 GEMM ----
// LDS overlaid (bin 31.0 KB | gemm1 wl 32 KB -> 32 KB static). Independent work.
struct BinSh {
    int cnt[512];
    int off[512];
    int gbase[512];
    int sd[256];
    unsigned int buf[B1CHUNK];
    unsigned short bid[B1CHUNK];
};
struct G1Sh {
    _Float16 wl[16384];
};

__global__ __launch_bounds__(256) void binGemm1_k(const int* __restrict__ src, const int* __restrict__ dst,
                                                  int* __restrict__ gcnt, unsigned int* __restrict__ slab,
                                                  int E, int nbuck, int nbin,
                                                  const float* __restrict__ A, const _Float16* __restrict__ wfrag,
                                                  __half* __restrict__ C, int n, int ntiles) {
    __shared__ __align__(16) char smem[32768];
    int t = threadIdx.x;
    if (blockIdx.x >= nbin) {
        // ---- layer-1 GEMM: C_perm = raw f16(A @ W1), direct-A, no dinv ----
        _Float16* wl = ((G1Sh*)smem)->wl;
        const int wv_ = t >> 6;
        const int lane = t & 63;
        const int m = lane & 15;
        const int q = lane >> 4;
        for (int c = t; c < 2048; c += 256)
            *(f16x8*)&wl[c * 8] = *(const f16x8*)&wfrag[c * 8];
        __syncthreads();
        int t0 = (blockIdx.x - nbin) * TPB1;
        int tend = t0 + TPB1;
        if (tend > ntiles) tend = ntiles;
        for (int tile = t0; tile < tend; ++tile) {
            int row0 = tile * 64;
            int ga = row0 + wv_ * 16 + m;
            f16x8 af[4];
            if (ga < n) {
#pragma unroll
                for (int kc = 0; kc < 4; ++kc)
                    af[kc] = ldA8(&A[(size_t)ga * DFEAT + kc * 32 + q * 8]);
            } else {
#pragma unroll
                for (int kc = 0; kc < 4; ++kc) af[kc] = zero8();
            }
            f32x4 acc[8];
#pragma unroll
            for (int ct = 0; ct < 8; ++ct) acc[ct] = (f32x4){0.f, 0.f, 0.f, 0.f};
#pragma unroll
            for (int ct = 0; ct < 8; ++ct) {
#pragma unroll
                for (int kc = 0; kc < 4; ++kc) {
                    f16x8 bf = *(f16x8*)&wl[((ct * 4 + kc) * 64 + lane) * 8];
                    acc[ct] = __builtin_amdgcn_mfma_f32_16x16x32_f16(af[kc], bf, acc[ct], 0, 0, 0);
                }
            }
            const int rbase = row0 + wv_ * 16 + q * 4;
#pragma unroll
            for (int r = 0; r < 4; ++r) {
                int gr = rbase + r;
                if (gr < n) {
                    f16x8 o;
#pragma unroll
                    for (int ct = 0; ct < 8; ++ct) o[ct] = (_Float16)acc[ct][r];
                    *(f16x8*)&C[(size_t)gr * DFEAT + m * 8] = o;
                }
            }
        }
        return;
    }
    // ---- bin body (R6-proven, via overlay) ----
    BinSh* B = (BinSh*)smem;
    int base = blockIdx.x * B1CHUNK;
    int nloc = E - base;
    if (nloc > B1CHUNK) nloc = B1CHUNK;
    B->cnt[t] = 0;
    B->cnt[t + 256] = 0;
    __syncthreads();
    int k = t;
    for (; k + 768 < nloc; k += 1024) {
        int d0 = dst[base + k], d1 = dst[base + k + 256], d2 = dst[base + k + 512], d3 = dst[base + k + 768];
        atomicAdd(&B->cnt[d0 >> BSHIFT], 1);
        atomicAdd(&B->cnt[d1 >> BSHIFT], 1);
        atomicAdd(&B->cnt[d2 >> BSHIFT], 1);
        atomicAdd(&B->cnt[d3 >> BSHIFT], 1);
    }
    for (; k < nloc; k += 256) atomicAdd(&B->cnt[dst[base + k] >> BSHIFT], 1);
    __syncthreads();
    int v0 = B->cnt[2 * t], v1 = B->cnt[2 * t + 1];
    int tsum = v0 + v1;
    B->sd[t] = tsum;
    __syncthreads();
    for (int o = 1; o < 256; o <<= 1) {
        int x = (t >= o) ? B->sd[t - o] : 0;
        __syncthreads();
        B->sd[t] += x;
        __syncthreads();
    }
    int texcl = B->sd[t] - tsum;
    B->off[2 * t] = texcl;
    B->off[2 * t + 1] = texcl + v0;
    if (2 * t < nbuck && v0 > 0) B->gbase[2 * t] = atomicAdd(&gcnt[2 * t], v0);
    if (2 * t + 1 < nbuck && v1 > 0) B->gbase[2 * t + 1] = atomicAdd(&gcnt[2 * t + 1], v1);
    __syncthreads();
    k = t;
    for (; k + 768 < nloc; k += 1024) {
        int d0 = dst[base + k], d1 = dst[base + k + 256], d2 = dst[base + k + 512], d3 = dst[base + k + 768];
        int s0 = src[base + k], s1 = src[base + k + 256], s2 = src[base + k + 512], s3 = src[base + k + 768];
        int b0_ = d0 >> BSHIFT, b1_ = d1 >> BSHIFT, b2_ = d2 >> BSHIFT, b3_ = d3 >> BSHIFT;
        int r0 = atomicAdd(&B->off[b0_], 1); B->buf[r0] = ((unsigned)s0 << BSHIFT) | (unsigned)(d0 & (BNODES - 1)); B->bid[r0] = (unsigned short)b0_;
        int r1 = atomicAdd(&B->off[b1_], 1); B->buf[r1] = ((unsigned)s1 << BSHIFT) | (unsigned)(d1 & (BNODES - 1)); B->bid[r1] = (unsigned short)b1_;
        int r2 = atomicAdd(&B->off[b2_], 1); B->buf[r2] = ((unsigned)s2 << BSHIFT) | (unsigned)(d2 & (BNODES - 1)); B->bid[r2] = (unsigned short)b2_;
        int r3 = atomicAdd(&B->off[b3_], 1); B->buf[r3] = ((unsigned)s3 << BSHIFT) | (unsigned)(d3 & (BNODES - 1)); B->bid[r3] = (unsigned short)b3_;
    }
    for (; k < nloc; k += 256) {
        int d = dst[base + k];
        int s = src[base + k];
        int b = d >> BSHIFT;
        int r = atomicAdd(&B->off[b], 1);
        B->buf[r] = ((unsigned)s << BSHIFT) | (unsigned)(d & (BNODES - 1));
        B->bid[r] = (unsigned short)b;
    }
    __syncthreads();
    k = t;
    for (; k + 768 < nloc; k += 1024) {
#pragma unroll
        for (int u = 0; u < 4; ++u) {
            int kk = k + u * 256;
            int b = B->bid[kk];
            int o0 = B->off[b] - B->cnt[b];
            int pos = B->gbase[b] + (kk - o0);
            if (pos < SLABC) slab[(size_t)b * SLABC + pos] = B->buf[kk];
        }
    }
    for (; k < nloc; k += 256) {
        int b = B->bid[k];
        int o0 = B->off[b] - B->cnt[b];
        int pos = B->gbase[b] + (k - o0);
        if (pos < SLABC) slab[(size_t)b * SLABC + pos] = B->buf[k];
    }
}

// ---- Phase B2: per-bucket degree count + rp + dinv + CSR col scatter ----
__global__ __launch_bounds__(256) void bucketAB_k(const unsigned int* __restrict__ slab,
                                                  const int* __restrict__ gcnt,
                                                  int* __restrict__ rp, float* __restrict__ dinv,
                                                  int* __restrict__ cols, int N, int nbuck) {
    __shared__ int cnt[256];
    __shared__ int cur[256];
    __shared__ int psum[256];
    __shared__ int outb[SLABC];
    int t = threadIdx.x;
    int b = blockIdx.x;
    int n0 = b << BSHIFT;
    int nn = N - n0;
    if (nn > BNODES) nn = BNODES;
    int ne_raw = gcnt[b];
    int ne = ne_raw > SLABC ? SLABC : ne_raw;
    const unsigned int* sl = slab + (size_t)b * SLABC;
    int part = 0;
    for (int i = t; i < b; i += 256) part += gcnt[i];
    psum[t] = part;
    cnt[t] = 0;
    __syncthreads();
    for (int o = 128; o > 0; o >>= 1) {
        if (t < o) psum[t] += psum[t + o];
        __syncthreads();
    }
    int base = psum[0];
    int k = t;
    for (; k + 768 < ne; k += 1024) {
        unsigned a0 = sl[k], a1 = sl[k + 256], a2 = sl[k + 512], a3 = sl[k + 768];
        atomicAdd(&cnt[a0 & (BNODES - 1)], 1);
        atomicAdd(&cnt[a1 & (BNODES - 1)], 1);
        atomicAdd(&cnt[a2 & (BNODES - 1)], 1);
        atomicAdd(&cnt[a3 & (BNODES - 1)], 1);
    }
    for (; k < ne; k += 256) atomicAdd(&cnt[sl[k] & (BNODES - 1)], 1);
    __syncthreads();
    int deg = cnt[t];
    for (int o = 1; o < 256; o <<= 1) {
        int x = (t >= o) ? cnt[t - o] : 0;
        __syncthreads();
        cnt[t] += x;
        __syncthreads();
    }
    int excl = cnt[t] - deg;
    if (t < nn) {
        rp[n0 + t] = base + excl;
        dinv[n0 + t] = rsqrtf((float)(deg + 1));  // +1 self loop
    }
    if (b == nbuck - 1 && t == 0) rp[N] = base + ne_raw;
    cur[t] = excl;
    __syncthreads();
    k = t;
    for (; k + 768 < ne; k += 1024) {
        unsigned a0 = sl[k], a1 = sl[k + 256], a2 = sl[k + 512], a3 = sl[k + 768];
        int p0 = atomicAdd(&cur[a0 & (BNODES - 1)], 1); outb[p0] = (int)(a0 >> BSHIFT);
        int p1 = atomicAdd(&cur[a1 & (BNODES - 1)], 1); outb[p1] = (int)(a1 >> BSHIFT);
        int p2 = atomicAdd(&cur[a2 & (BNODES - 1)], 1); outb[p2] = (int)(a2 >> BSHIFT);
        int p3 = atomicAdd(&cur[a3 & (BNODES - 1)], 1); outb[p3] = (int)(a3 >> BSHIFT);
    }
    for (; k < ne; k += 256) {
        unsigned a = sl[k];
        int p = atomicAdd(&cur[a & (BNODES - 1)], 1);
        outb[p] = (int)(a >> BSHIFT);
    }
    __syncthreads();
    k = t;
    for (; k + 768 < ne; k += 1024) {
        int o0 = outb[k], o1 = outb[k + 256], o2 = outb[k + 512], o3 = outb[k + 768];
        cols[base + k] = o0;
        cols[base + k + 256] = o1;
        cols[base + k + 512] = o2;
        cols[base + k + 768] = o3;
    }
    for (; k < ne; k += 256) cols[base + k] = outb[k];
}

// ---------------- standalone staged GEMM (layers 2-3): R6-proven staged-A + W-LDS ----------------
template <typename TIN>
__global__ __launch_bounds__(256) void gemmP_k(const TIN* __restrict__ A, const _Float16* __restrict__ wfrag,
                                               const float* __restrict__ dinv, __half* __restrict__ C,
                                               int n, int ntiles) {
    __shared__ _Float16 al[8192];     // A frags, swizzled (16 KB)
    __shared__ _Float16 wl[16384];    // W frags, linear copy (32 KB)
    const int tid = threadIdx.x;
    const int wv_ = tid >> 6;
    const int lane = tid & 63;
    const int t0 = blockIdx.x * TPB_TILES;
    const int chunk = tid & 15;
    const int rsub = tid >> 4;
    const int kcS = chunk >> 2, quadS = chunk & 3;
    const int swzS = (kcS << 1) ^ (quadS & 1);

    for (int c = tid; c < 2048; c += 256)
        *(f16x8*)&wl[c * 8] = *(const f16x8*)&wfrag[c * 8];

    f16x8 pre[4];
    {
        int row0 = t0 * 64;
#pragma unroll
        for (int p = 0; p < 4; ++p) {
            int gr = row0 + p * 16 + rsub;
            pre[p] = (gr < n) ? ldA8(&A[(size_t)gr * DFEAT + chunk * 8]) : zero8();
        }
    }
    for (int tt = 0; tt < TPB_TILES; ++tt) {
        int tile = t0 + tt;
        if (tile >= ntiles) break;
        int row0 = tile * 64;
#pragma unroll
        for (int p = 0; p < 4; ++p) {
            int idx = (p * 4 + kcS) * 64 + quadS * 16 + rsub;
            *(f16x8*)&al[(idx ^ swzS) * 8] = pre[p];
        }
        __syncthreads();
        if (tt + 1 < TPB_TILES && tile + 1 < ntiles) {
            int nrow0 = (tile + 1) * 64;
#pragma unroll
            for (int p = 0; p < 4; ++p) {
                int gr = nrow0 + p * 16 + rsub;
                pre[p] = (gr < n) ? ldA8(&A[(size_t)gr * DFEAT + chunk * 8]) : zero8();
            }
        }
        f16x8 af[4];
        const int swzR = (lane >> 4) & 1;
#pragma unroll
        for (int kc = 0; kc < 4; ++kc) {
            int idx = (wv_ * 4 + kc) * 64 + lane;
            af[kc] = *(f16x8*)&al[(idx ^ (kc << 1) ^ swzR) * 8];
        }
        const int quad = lane >> 4, cb = lane & 15;
        const int rbase = row0 + wv_ * 16 + quad * 4;
        float ds[4];
#pragma unroll
        for (int r = 0; r < 4; ++r) ds[r] = (rbase + r < n) ? dinv[rbase + r] : 0.f;
        f32x4 acc[8];
#pragma unroll
        for (int ct = 0; ct < 8; ++ct) acc[ct] = (f32x4){0.f, 0.f, 0.f, 0.f};
#pragma unroll
        for (int ct = 0; ct < 8; ++ct) {
#pragma unroll
            for (int kc = 0; kc < 4; ++kc) {
                f16x8 bf = *(f16x8*)&wl[((ct * 4 + kc) * 64 + lane) * 8];
                acc[ct] = __builtin_amdgcn_mfma_f32_16x16x32_f16(af[kc], bf, acc[ct], 0, 0, 0);
            }
        }
#pragma unroll
        for (int r = 0; r < 4; ++r) {
            int gr = rbase + r;
            if (gr < n) {
                f16x8 o;
#pragma unroll
                for (int ct = 0; ct < 8; ++ct) o[ct] = (_Float16)(acc[ct][r] * ds[r]);
                *(f16x8*)&C[(size_t)gr * DFEAT + cb * 8] = o;
            }
        }
        __syncthreads();
    }
}

// ---------------- aggregation (permuted feature space) ----------------
// One wave per node, half2 per lane (fabric-bound floor; do not perturb structure).

// layer-1 variant: per-edge weight dinv[c] (L2-resident 400 KB, scalar load via SGPR c)
__global__ __launch_bounds__(256) void aggW_k(const __half* __restrict__ T, const float* __restrict__ dinv,
                                              const int* __restrict__ rowptr, const int* __restrict__ cols,
                                              const float* __restrict__ biasp,
                                              __half* __restrict__ out, int n) {
    int wid = (int)((blockIdx.x * (size_t)blockDim.x + threadIdx.x) >> 6);
    int lane = threadIdx.x & 63;
    if (wid >= n) return;
    int fb = lane * 2;
    float di = dinv[wid];
    float2 t0 = __half22float2(*(const __half2*)(T + (size_t)wid * DFEAT + fb));
    float ax = di * t0.x;
    float ay = di * t0.y;
    int s = rowptr[wid], e = rowptr[wid + 1];
    for (int p = s; p < e; ) {
        int take = e - p;
        if (take > 64) take = 64;
        int q = p + lane;
        if (q >= e) q = e - 1;
        int ci = cols[q];
        int j = 0;
        for (; j + 8 <= take; j += 8) {
            int c0 = __builtin_amdgcn_readlane(ci, j + 0);
            int c1 = __builtin_amdgcn_readlane(ci, j + 1);
            int c2 = __builtin_amdgcn_readlane(ci, j + 2);
            int c3 = __builtin_amdgcn_readlane(ci, j + 3);
            int c4 = __builtin_amdgcn_readlane(ci, j + 4);
            int c5 = __builtin_amdgcn_readlane(ci, j + 5);
            int c6 = __builtin_amdgcn_readlane(ci, j + 6);
            int c7 = __builtin_amdgcn_readlane(ci, j + 7);
            float w0 = dinv[c0], w1 = dinv[c1], w2 = dinv[c2], w3 = dinv[c3];
            float w4 = dinv[c4], w5 = dinv[c5], w6 = dinv[c6], w7 = dinv[c7];
            float2 v0 = __half22float2(*(const __half2*)(T + (size_t)c0 * DFEAT + fb));
            float2 v1 = __half22float2(*(const __half2*)(T + (size_t)c1 * DFEAT + fb));
            float2 v2 = __half22float2(*(const __half2*)(T + (size_t)c2 * DFEAT + fb));
            float2 v3 = __half22float2(*(const __half2*)(T + (size_t)c3 * DFEAT + fb));
            float2 v4 = __half22float2(*(const __half2*)(T + (size_t)c4 * DFEAT + fb));
            float2 v5 = __half22float2(*(const __half2*)(T + (size_t)c5 * DFEAT + fb));
            float2 v6 = __half22float2(*(const __half2*)(T + (size_t)c6 * DFEAT + fb));
            float2 v7 = __half22float2(*(const __half2*)(T + (size_t)c7 * DFEAT + fb));
            ax += w0 * v0.x; ay += w0 * v0.y;
            ax += w1 * v1.x; ay += w1 * v1.y;
            ax += w2 * v2.x; ay += w2 * v2.y;
            ax += w3 * v3.x; ay += w3 * v3.y;
            ax += w4 * v4.x; ay += w4 * v4.y;
            ax += w5 * v5.x; ay += w5 * v5.y;
            ax += w6 * v6.x; ay += w6 * v6.y;
            ax += w7 * v7.x; ay += w7 * v7.y;
        }
        for (; j < take; ++j) {
            int c = __builtin_amdgcn_readlane(ci, j);
            float w = dinv[c];
            float2 v = __half22float2(*(const __half2*)(T + (size_t)c * DFEAT + fb));
            ax += w * v.x; ay += w * v.y;
        }
        p += take;
    }
    float ox = fmaxf(di * ax + biasp[fb], 0.f);
    float oy = fmaxf(di * ay + biasp[fb + 1], 0.f);
    *(__half2*)(out + (size_t)wid * DFEAT + fb) = __floats2half2_rn(ox, oy);
}

__device__ inline float2 agg_row(const __half* __restrict__ T, const int* __restrict__ rowptr,
                                 const int* __restrict__ cols, int wid, int lane, int fb) {
    float2 t0 = __half22float2(*(const __half2*)(T + (size_t)wid * DFEAT + fb));
    float ax = t0.x;
    float ay = t0.y;
    int s = rowptr[wid], e = rowptr[wid + 1];
    for (int p = s; p < e; ) {
        int take = e - p;
        if (take > 64) take = 64;
        int q = p + lane;
        if (q >= e) q = e - 1;
        int ci = cols[q];
        int j = 0;
        for (; j + 8 <= take; j += 8) {
            int c0 = __builtin_amdgcn_readlane(ci, j + 0);
            int c1 = __builtin_amdgcn_readlane(ci, j + 1);
            int c2 = __builtin_amdgcn_readlane(ci, j + 2);
            int c3 = __builtin_amdgcn_readlane(ci, j + 3);
            int c4 = __builtin_amdgcn_readlane(ci, j + 4);
            int c5 = __builtin_amdgcn_readlane(ci, j + 5);
            int c6 = __builtin_amdgcn_readlane(ci, j + 6);
            int c7 = __builtin_amdgcn_readlane(ci, j + 7);
            float2 v0 = __half22float2(*(const __half2*)(T + (size_t)c0 * DFEAT + fb));
            float2 v1 = __half22float2(*(const __half2*)(T + (size_t)c1 * DFEAT + fb));
            float2 v2 = __half22float2(*(const __half2*)(T + (size_t)c2 * DFEAT + fb));
            float2 v3 = __half22float2(*(const __half2*)(T + (size_t)c3 * DFEAT + fb));
            float2 v4 = __half22float2(*(const __half2*)(T + (size_t)c4 * DFEAT + fb));
            float2 v5 = __half22float2(*(const __half2*)(T + (size_t)c5 * DFEAT + fb));
            float2 v6 = __half22float2(*(const __half2*)(T + (size_t)c6 * DFEAT + fb));
            float2 v7 = __half22float2(*(const __half2*)(T + (size_t)c7 * DFEAT + fb));
            ax += v0.x; ay += v0.y;
            ax += v1.x; ay += v1.y;
            ax += v2.x; ay += v2.y;
            ax += v3.x; ay += v3.y;
            ax += v4.x; ay += v4.y;
            ax += v5.x; ay += v5.y;
            ax += v6.x; ay += v6.y;
            ax += v7.x; ay += v7.y;
        }
        for (; j < take; ++j) {
            int c = __builtin_amdgcn_readlane(ci, j);
            float2 v = __half22float2(*(const __half2*)(T + (size_t)c * DFEAT + fb));
            ax += v.x; ay += v.y;
        }
        p += take;
    }
    return make_float2(ax, ay);
}

__global__ __launch_bounds__(256) void agg_k(const __half* __restrict__ T, const float* __restrict__ dinv,
                                             const int* __restrict__ rowptr, const int* __restrict__ cols,
                                             const float* __restrict__ biasp,
                                             __half* __restrict__ out, int n) {
    int wid = (int)((blockIdx.x * (size_t)blockDim.x + threadIdx.x) >> 6);
    int lane = threadIdx.x & 63;
    if (wid >= n) return;
    int fb = lane * 2;
    float2 a = agg_row(T, rowptr, cols, wid, lane, fb);
    float dw = dinv[wid];
    float ox = fmaxf(dw * a.x + biasp[fb], 0.f);
    float oy = fmaxf(dw * a.y + biasp[fb + 1], 0.f);
    *(__half2*)(out + (size_t)wid * DFEAT + fb) = __floats2half2_rn(ox, oy);
}

__global__ __launch_bounds__(256) void aggF_k(const __half* __restrict__ T, const float* __restrict__ dinv,
                                              const int* __restrict__ rowptr, const int* __restrict__ cols,
                                              const float* __restrict__ biasp,
                                              float* __restrict__ out, int n) {
    int wid = (int)((blockIdx.x * (size_t)blockDim.x + threadIdx.x) >> 6);
    int lane = threadIdx.x & 63;
    if (wid >= n) return;
    int fb = lane * 2;
    float2 a = agg_row(T, rowptr, cols, wid, lane, fb);
    float dw = dinv[wid];
    float ox = dw * a.x + biasp[fb];
    float oy = dw * a.y + biasp[fb + 1];
    int c0 = ((fb & 7) << 4) | (fb >> 3);
    int c1 = (((fb + 1) & 7) << 4) | ((fb + 1) >> 3);
    out[(size_t)wid * DFEAT + c0] = ox;
    out[(size_t)wid * DFEAT + c1] = oy;
}

// ---------------- launch ----------------

extern "C" void kernel_launch(void* const* d_in, const int* in_sizes, int n_in,
                              void* d_out, int out_size, void* d_ws, size_t ws_size,
                              hipStream_t stream) {
    const float* x  = (const float*)d_in[0];
    const int*   ei = (const int*)d_in[1];
    const float* W1 = (const float*)d_in[2];
    const float* b1 = (const float*)d_in[3];
    const float* W2 = (const float*)d_in[4];
    const float* b2 = (const float*)d_in[5];
    const float* W3 = (const float*)d_in[6];
    const float* b3 = (const float*)d_in[7];
    float* out = (float*)d_out;

    const int N = in_sizes[0] / DFEAT;
    const int E = in_sizes[1] / 2;
    const int* srcp = ei;
    const int* dstp = ei + E;

    size_t off = 0;
    auto alloc = [&](size_t bytes) -> void* {
        void* p = (char*)d_ws + off;
        off += (bytes + 255) & ~(size_t)255;
        return p;
    };
    const int nbuck = (N + BNODES - 1) / BNODES;       // 391 for N=100000 (<=512)

    int*    gcnt = (int*)alloc(2048);
    int*    rp   = (int*)alloc((size_t)(N + 1) * 4);
    float*  dinv = (float*)alloc((size_t)N * 4);
    _Float16* wpk = (_Float16*)alloc((size_t)3 * 16384 * 2);   // pre-packed W frags
    float*  bp   = (float*)alloc(3 * 128 * 4);                 // permuted biases
    unsigned int* slab = (unsigned int*)alloc((size_t)nbuck * SLABC * 4);
    int*    cols = (int*)alloc((size_t)E * 4);
    __half* bufA = (__half*)alloc((size_t)N * DFEAT * 2);      // T' ping
    __half* bufB = (__half*)alloc((size_t)N * DFEAT * 2);      // agg pong

    const int nbin = (E + B1CHUNK - 1) / B1CHUNK;
    int ntiles = (N + 63) / 64;
    int g1blocks = (ntiles + TPB1 - 1) / TPB1;
    int gemmGrid = (ntiles + TPB_TILES - 1) / TPB_TILES;
    int aggGrid  = (int)(((size_t)N * 64 + 255) / 256);

    // 1: W pack (zeroes gcnt).  2: fused [bin | gemm1-raw] — gemm1 hides under bin.
    packW_k<<<192, 256, 0, stream>>>(W1, W2, W3, b1, b2, b3, wpk, bp, gcnt);
    binGemm1_k<<<nbin + g1blocks, 256, 0, stream>>>(srcp, dstp, gcnt, slab, E, nbuck, nbin,
                                                    x, wpk, bufA, N, ntiles);
    bucketAB_k<<<nbuck, 256, 0, stream>>>(slab, gcnt, rp, dinv, cols, N, nbuck);

    aggW_k<<<aggGrid, 256, 0, stream>>>(bufA, dinv, rp, cols, bp, bufB, N);

    gemmP_k<__half><<<gemmGrid, 256, 0, stream>>>(bufB, wpk + 16384, dinv, bufA, N, ntiles);
    agg_k<<<aggGrid, 256, 0, stream>>>(bufA, dinv, rp, cols, bp + 128, bufB, N);

    gemmP_k<__half><<<gemmGrid, 256, 0, stream>>>(bufB, wpk + 32768, dinv, bufA, N, ntiles);
    aggF_k<<<aggGrid, 256, 0, stream>>>(bufA, dinv, rp, cols, bp + 256, out, N);
}